// Round 5
// baseline (167.465 us; speedup 1.0000x reference)
//
#include <hip/hip_runtime.h>
#include <hip/hip_bf16.h>

// Renderer vertex-normals rev14. Math FROZEN from rev8 (passing, absmax = 1 bf16 ulp):
//   cross: c_i = fmaf(a_p, b_q, -pinned(a_q*b_p))  (uniform LHS fusion)
//   norms: (x*x + y*y) + z*z, sqrtf, fmaxf(n,1e-12f), IEEE '/'
//   vertex sum: c = 0..5 sequential per (v,batch) accumulator
// Kept from rev12/13: batch-interleaved 64-B tables, quad-split lane mapping
//   (quad's 4 lanes share one 64-B entry -> 1 line/quad at the TA), nt stores.
// Rev14 (layout/scheduling only; per-element math identical):
//   VERTEX (was 44 us, FETCH 122.7 MB vs ~70 compulsory, VALU 13% ->
//   latency-bound + L2 pollution):
//     - VPT=2: thread (q,bl) handles v0=q and v1=q+V/2. 12 table loads, then
//       12 INDEPENDENT quad-merged gathers in flight (~2x MLP).
//     - vti/vtw loads nontemporal: read-once tables (3.1 MB/XCD) no longer
//       evict the 8.3 MB fnI slice being re-touched ~3x/line.
//   FACE: FPT=3 (F%3==0 exactly): 9 independent gathers, ~58 VGPR, under the
//   64-VGPR occupancy cliff. Same mechanism that took face 44 -> ~30 us.
// bs=32, V=65536, F=130050, C=6.

#define XCDS 8
#define BPX  4   // batches per XCD; fast path requires bs == XCDS*BPX == 32
#define FPT  3   // faces per thread in the face pass (requires F % FPT == 0)

typedef float f32x4 __attribute__((ext_vector_type(4)));
typedef float f32x2 __attribute__((ext_vector_type(2)));
typedef int   i32x2 __attribute__((ext_vector_type(2)));

__device__ __forceinline__ float mulf_pin(float a, float b) {
  float t = a * b;
  asm("" : "+v"(t));   // pin: separately-rounded f32 product, cannot re-fuse
  return t;
}

__device__ __forceinline__ float3 cross_lhs(float ax, float ay, float az,
                                            float bx, float by, float bz) {
  float cx = __builtin_fmaf(ay, bz, -mulf_pin(az, by));
  float cy = __builtin_fmaf(az, bx, -mulf_pin(ax, bz));
  float cz = __builtin_fmaf(ax, by, -mulf_pin(ay, bx));
  return make_float3(cx, cy, cz);
}

__device__ __forceinline__ void nt_store_f4(float4* p, float x, float y,
                                            float z, float w) {
  f32x4 r;
  r[0] = x; r[1] = y; r[2] = z; r[3] = w;
  __builtin_nontemporal_store(r, (f32x4*)p);
}

// ---------------- Kernel A: batch-interleaved point pack, quad-split -------
__global__ __launch_bounds__(256) void rend14_pack(
    const float* __restrict__ points,   // (bs, 3, V)
    float4*      __restrict__ ptsI,     // (XCDS, V, BPX)
    int V) {
  int xcd = blockIdx.x % XCDS;
  int g   = (blockIdx.x / XCDS) * 256 + threadIdx.x;
  int v   = g >> 2;
  int bl  = g & 3;
  int b   = xcd * BPX + bl;
  const float* pb = points + (size_t)b * 3 * V;
  float x = __builtin_nontemporal_load(pb + v);
  float y = __builtin_nontemporal_load(pb + V + v);
  float z = __builtin_nontemporal_load(pb + 2 * V + v);
  ptsI[((size_t)xcd * V + v) * BPX + bl] = make_float4(x, y, z, 0.0f);
}

// ---------------- Kernel B: face normals, quad-split, FPT=3 ----------------
// Thread (q, bl) handles f_k = q + k*Q (Q = F/3): 9 index loads, then 9
// independent quad-merged 64-B gathers in flight, then three frozen
// compute+store sequences. Per-face math identical -> bit-identical.
__global__ __launch_bounds__(256) void rend14_face(
    const float4* __restrict__ ptsI,    // (XCDS, V, BPX)
    const int*    __restrict__ faces,   // (F, 3)
    float4*       __restrict__ fnI,     // (XCDS, F, BPX)
    int F, int V, int Q) {
  int xcd = blockIdx.x % XCDS;
  int g   = (blockIdx.x / XCDS) * 256 + threadIdx.x;
  int q   = g >> 2;
  int bl  = g & 3;
  if (q >= Q) return;

  int f0 = q;
  int f1 = q + Q;
  int f2 = q + 2 * Q;

  int a0 = __builtin_nontemporal_load(faces + 3 * f0 + 0);
  int a1 = __builtin_nontemporal_load(faces + 3 * f0 + 1);
  int a2 = __builtin_nontemporal_load(faces + 3 * f0 + 2);
  int b0 = __builtin_nontemporal_load(faces + 3 * f1 + 0);
  int b1 = __builtin_nontemporal_load(faces + 3 * f1 + 1);
  int b2 = __builtin_nontemporal_load(faces + 3 * f1 + 2);
  int c0 = __builtin_nontemporal_load(faces + 3 * f2 + 0);
  int c1 = __builtin_nontemporal_load(faces + 3 * f2 + 1);
  int c2 = __builtin_nontemporal_load(faces + 3 * f2 + 2);

  const float4* P = ptsI + (size_t)xcd * V * BPX;
  float4 pa0 = P[(size_t)a0 * BPX + bl];
  float4 pa1 = P[(size_t)a1 * BPX + bl];
  float4 pa2 = P[(size_t)a2 * BPX + bl];
  float4 pb0 = P[(size_t)b0 * BPX + bl];
  float4 pb1 = P[(size_t)b1 * BPX + bl];
  float4 pb2 = P[(size_t)b2 * BPX + bl];
  float4 pc0 = P[(size_t)c0 * BPX + bl];
  float4 pc1 = P[(size_t)c1 * BPX + bl];
  float4 pc2 = P[(size_t)c2 * BPX + bl];

  {
    float ax = pa1.x - pa0.x, ay = pa1.y - pa0.y, az = pa1.z - pa0.z;
    float bx = pa2.x - pa0.x, by = pa2.y - pa0.y, bz = pa2.z - pa0.z;
    float3 c = cross_lhs(ax, ay, az, bx, by, bz);
    float n = sqrtf((c.x * c.x + c.y * c.y) + c.z * c.z);
    float d = fmaxf(n, 1e-12f);
    nt_store_f4(fnI + ((size_t)xcd * F + f0) * BPX + bl,
                c.x / d, c.y / d, c.z / d, 0.0f);
  }
  {
    float ax = pb1.x - pb0.x, ay = pb1.y - pb0.y, az = pb1.z - pb0.z;
    float bx = pb2.x - pb0.x, by = pb2.y - pb0.y, bz = pb2.z - pb0.z;
    float3 c = cross_lhs(ax, ay, az, bx, by, bz);
    float n = sqrtf((c.x * c.x + c.y * c.y) + c.z * c.z);
    float d = fmaxf(n, 1e-12f);
    nt_store_f4(fnI + ((size_t)xcd * F + f1) * BPX + bl,
                c.x / d, c.y / d, c.z / d, 0.0f);
  }
  {
    float ax = pc1.x - pc0.x, ay = pc1.y - pc0.y, az = pc1.z - pc0.z;
    float bx = pc2.x - pc0.x, by = pc2.y - pc0.y, bz = pc2.z - pc0.z;
    float3 c = cross_lhs(ax, ay, az, bx, by, bz);
    float n = sqrtf((c.x * c.x + c.y * c.y) + c.z * c.z);
    float d = fmaxf(n, 1e-12f);
    nt_store_f4(fnI + ((size_t)xcd * F + f2) * BPX + bl,
                c.x / d, c.y / d, c.z / d, 0.0f);
  }
}

// ---------------- Kernel C: vertex normals, quad-split, VPT=2 --------------
// Thread (q, bl) handles v0=q, v1=q+H (H=V/2). 12 nt table loads (read-once
// data stays out of fnI's L2), then 12 independent quad-merged gathers in
// flight, then two frozen c=0..5 accumulate+store sequences.
__global__ __launch_bounds__(256) void rend14_vertex(
    const float4* __restrict__ fnI,     // (XCDS, F, BPX)
    const int*    __restrict__ vti,     // (V, 6)
    const float*  __restrict__ vtw,     // (V, 6)
    float*        __restrict__ out,     // (bs, V, 3)
    int F, int V, int H) {
  int xcd = blockIdx.x % XCDS;
  int g   = (blockIdx.x / XCDS) * 256 + threadIdx.x;
  int q   = g >> 2;
  int bl  = g & 3;
  if (q >= H) return;
  int v0 = q;
  int v1 = q + H;

  i32x2 ta0 = __builtin_nontemporal_load((const i32x2*)(vti + (size_t)v0 * 6) + 0);
  i32x2 ta1 = __builtin_nontemporal_load((const i32x2*)(vti + (size_t)v0 * 6) + 1);
  i32x2 ta2 = __builtin_nontemporal_load((const i32x2*)(vti + (size_t)v0 * 6) + 2);
  f32x2 wa0 = __builtin_nontemporal_load((const f32x2*)(vtw + (size_t)v0 * 6) + 0);
  f32x2 wa1 = __builtin_nontemporal_load((const f32x2*)(vtw + (size_t)v0 * 6) + 1);
  f32x2 wa2 = __builtin_nontemporal_load((const f32x2*)(vtw + (size_t)v0 * 6) + 2);
  i32x2 tb0 = __builtin_nontemporal_load((const i32x2*)(vti + (size_t)v1 * 6) + 0);
  i32x2 tb1 = __builtin_nontemporal_load((const i32x2*)(vti + (size_t)v1 * 6) + 1);
  i32x2 tb2 = __builtin_nontemporal_load((const i32x2*)(vti + (size_t)v1 * 6) + 2);
  f32x2 wb0 = __builtin_nontemporal_load((const f32x2*)(vtw + (size_t)v1 * 6) + 0);
  f32x2 wb1 = __builtin_nontemporal_load((const f32x2*)(vtw + (size_t)v1 * 6) + 1);
  f32x2 wb2 = __builtin_nontemporal_load((const f32x2*)(vtw + (size_t)v1 * 6) + 2);

  int   ia[6] = {ta0[0], ta0[1], ta1[0], ta1[1], ta2[0], ta2[1]};
  float wa[6] = {wa0[0], wa0[1], wa1[0], wa1[1], wa2[0], wa2[1]};
  int   ib[6] = {tb0[0], tb0[1], tb1[0], tb1[1], tb2[0], tb2[1]};
  float wb[6] = {wb0[0], wb0[1], wb1[0], wb1[1], wb2[0], wb2[1]};

  const float4* P = fnI + (size_t)xcd * F * BPX;
  float4 na0 = P[(size_t)ia[0] * BPX + bl];
  float4 na1 = P[(size_t)ia[1] * BPX + bl];
  float4 na2 = P[(size_t)ia[2] * BPX + bl];
  float4 na3 = P[(size_t)ia[3] * BPX + bl];
  float4 na4 = P[(size_t)ia[4] * BPX + bl];
  float4 na5 = P[(size_t)ia[5] * BPX + bl];
  float4 nb0 = P[(size_t)ib[0] * BPX + bl];
  float4 nb1 = P[(size_t)ib[1] * BPX + bl];
  float4 nb2 = P[(size_t)ib[2] * BPX + bl];
  float4 nb3 = P[(size_t)ib[3] * BPX + bl];
  float4 nb4 = P[(size_t)ib[4] * BPX + bl];
  float4 nb5 = P[(size_t)ib[5] * BPX + bl];

  int b = xcd * BPX + bl;
  {
    float sx = 0.f, sy = 0.f, sz = 0.f;
    sx += na0.x * wa[0]; sy += na0.y * wa[0]; sz += na0.z * wa[0];
    sx += na1.x * wa[1]; sy += na1.y * wa[1]; sz += na1.z * wa[1];
    sx += na2.x * wa[2]; sy += na2.y * wa[2]; sz += na2.z * wa[2];
    sx += na3.x * wa[3]; sy += na3.y * wa[3]; sz += na3.z * wa[3];
    sx += na4.x * wa[4]; sy += na4.y * wa[4]; sz += na4.z * wa[4];
    sx += na5.x * wa[5]; sy += na5.y * wa[5]; sz += na5.z * wa[5];
    float n = sqrtf((sx * sx + sy * sy) + sz * sz);
    float d = fmaxf(n, 1e-12f);
    size_t o = ((size_t)b * V + v0) * 3;
    __builtin_nontemporal_store(sx / d, out + o + 0);
    __builtin_nontemporal_store(sy / d, out + o + 1);
    __builtin_nontemporal_store(sz / d, out + o + 2);
  }
  {
    float sx = 0.f, sy = 0.f, sz = 0.f;
    sx += nb0.x * wb[0]; sy += nb0.y * wb[0]; sz += nb0.z * wb[0];
    sx += nb1.x * wb[1]; sy += nb1.y * wb[1]; sz += nb1.z * wb[1];
    sx += nb2.x * wb[2]; sy += nb2.y * wb[2]; sz += nb2.z * wb[2];
    sx += nb3.x * wb[3]; sy += nb3.y * wb[3]; sz += nb3.z * wb[3];
    sx += nb4.x * wb[4]; sy += nb4.y * wb[4]; sz += nb4.z * wb[4];
    sx += nb5.x * wb[5]; sy += nb5.y * wb[5]; sz += nb5.z * wb[5];
    float n = sqrtf((sx * sx + sy * sy) + sz * sz);
    float d = fmaxf(n, 1e-12f);
    size_t o = ((size_t)b * V + v1) * 3;
    __builtin_nontemporal_store(sx / d, out + o + 0);
    __builtin_nontemporal_store(sy / d, out + o + 1);
    __builtin_nontemporal_store(sz / d, out + o + 2);
  }
}

// ================= Fallback path (rev8, proven): ===========================
__global__ __launch_bounds__(256) void rend14_face_fb(
    const float* __restrict__ points,
    const int*   __restrict__ faces,
    float4*      __restrict__ fnorm,
    int F, int V) {
  int f = blockIdx.x * blockDim.x + threadIdx.x;
  int b = blockIdx.y;
  if (f >= F) return;

  int i0 = faces[3 * f + 0];
  int i1 = faces[3 * f + 1];
  int i2 = faces[3 * f + 2];

  const float* pb = points + (size_t)b * 3 * V;
  float ax = pb[i1] - pb[i0], ay = pb[V + i1] - pb[V + i0], az = pb[2 * V + i1] - pb[2 * V + i0];
  float bx = pb[i2] - pb[i0], by = pb[V + i2] - pb[V + i0], bz = pb[2 * V + i2] - pb[2 * V + i0];

  float3 c = cross_lhs(ax, ay, az, bx, by, bz);

  float n = sqrtf((c.x * c.x + c.y * c.y) + c.z * c.z);
  float d = fmaxf(n, 1e-12f);

  fnorm[(size_t)b * F + f] = make_float4(c.x / d, c.y / d, c.z / d, 0.0f);
}

__global__ __launch_bounds__(256) void rend14_vertex_fb(
    const float4* __restrict__ fnorm,
    const int*    __restrict__ vti,
    const float*  __restrict__ vtw,
    float*        __restrict__ out,
    int F, int V) {
  int v = blockIdx.x * blockDim.x + threadIdx.x;
  int b = blockIdx.y;
  if (v >= V) return;

  const float4* fb = fnorm + (size_t)b * F;
  float sx = 0.f, sy = 0.f, sz = 0.f;
#pragma unroll
  for (int c = 0; c < 6; ++c) {
    int    idx = vti[v * 6 + c];
    float  w   = vtw[v * 6 + c];
    float4 nr  = fb[idx];
    sx += nr.x * w;
    sy += nr.y * w;
    sz += nr.z * w;
  }
  float n = sqrtf((sx * sx + sy * sy) + sz * sz);
  float d = fmaxf(n, 1e-12f);
  size_t o = ((size_t)b * V + v) * 3;
  out[o + 0] = sx / d;
  out[o + 1] = sy / d;
  out[o + 2] = sz / d;
}

extern "C" void kernel_launch(void* const* d_in, const int* in_sizes, int n_in,
                              void* d_out, int out_size, void* d_ws, size_t ws_size,
                              hipStream_t stream) {
  const float* points = (const float*)d_in[0];
  const int*   faces  = (const int*)d_in[1];
  const int*   vti    = (const int*)d_in[2];
  const float* vtw    = (const float*)d_in[3];
  float*       out    = (float*)d_out;

  const int F  = in_sizes[1] / 3;                       // 130050
  const int V  = in_sizes[2] / 6;                       // 65536
  const int bs = (int)(in_sizes[0] / (3 * (size_t)V));  // 32

  const size_t ptsI_bytes = (size_t)bs * V * sizeof(float4);  // 33.6 MB
  const size_t fnI_bytes  = (size_t)bs * F * sizeof(float4);  // 66.6 MB

  const bool fast_ok = (ws_size >= ptsI_bytes + fnI_bytes) &&
                       (bs == XCDS * BPX) && (V % 512 == 0) && (F % FPT == 0);

  if (fast_ok) {
    float4* ptsI = (float4*)d_ws;
    float4* fnI  = (float4*)((char*)d_ws + ptsI_bytes);
    const int Q   = F / FPT;                        // 43350 face-triples
    const int H   = V / 2;                          // 32768 vertex-pairs
    const int ppb = (V * BPX) / 256;                // 1024 pack-blocks per XCD
    const int fqb = (Q * 4 + 255) / 256;            // 678 face-quad blocks per XCD
    const int vqb = (H * BPX) / 256;                // 512 vertex-quad blocks per XCD

    rend14_pack<<<dim3(XCDS * ppb), dim3(256), 0, stream>>>(points, ptsI, V);
    rend14_face<<<dim3(XCDS * fqb), dim3(256), 0, stream>>>(ptsI, faces, fnI, F, V, Q);
    rend14_vertex<<<dim3(XCDS * vqb), dim3(256), 0, stream>>>(fnI, vti, vtw, out, F, V, H);
  } else if (ws_size >= fnI_bytes) {  // rev8 fallback
    float4* fnorm = (float4*)d_ws;
    rend14_face_fb<<<dim3((F + 255) / 256, bs), dim3(256), 0, stream>>>(
        points, faces, fnorm, F, V);
    rend14_vertex_fb<<<dim3((V + 255) / 256, bs), dim3(256), 0, stream>>>(
        fnorm, vti, vtw, out, F, V);
  }
}